// Round 15
// baseline (77.854 us; speedup 1.0000x reference)
//
#include <hip/hip_runtime.h>
#include <hip/hip_bf16.h>
#include <stdint.h>

// SelfBallPointQuery: B=16, C=3, N=2048, RADIUS^2=0.04, MAX_SAMPLES=64.
// R15: two-phase. R14 post-mortem: single-kernel shape caps TLP at 16
// waves/CU (512 blocks, lane=query); the s_load->VALU chain needs more waves.
//  K1: 2048 blocks x 256 thr (32 waves/CU). Wave = (query-group, 128-pt
//      window); pure packed-v2f tests, SMEM point loads, writes 4 mask words
//      per lane COALESCED into d_out (region qg doubles as mask scratch:
//      64 words/query == 64 ints/query output row; block qg only ever
//      touches region qg in both kernels; K1->K2 visibility via stream order).
//  K2: 512 blocks x 512 thr: reload masks coalesced, then R14's proven
//      prefix/emit/LDS-rows/coalesced-copy-out over the same region.

#define B_DIM 16
#define N_PTS 2048
#define K_OUT 64
#define R2 0.04f
#define ROWPAD 65

typedef float v2f __attribute__((ext_vector_type(2)));

// ---------------- K1: dense mask build ----------------
// grid 2048 = 512 qg x 4 ; block 256 thr = 4 waves; wave -> one 128-pt window
__global__ __launch_bounds__(256, 8) void bq_mask_kernel(
    const float* __restrict__ pcs,   // (B, 3, N)
    int* __restrict__ out)           // masks: out[qg*4096 + w*64 + lane]
{
#pragma clang fp contract(off)
    const int bid  = blockIdx.x;
    const int qg   = bid >> 2;                 // 0..511 = b*32 + g
    const int b    = qg >> 5;
    const int g    = qg & 31;
    const int tid  = threadIdx.x;
    const int wave = __builtin_amdgcn_readfirstlane(tid >> 6); // uniform
    const int lane = tid & 63;
    const int win  = (bid & 3) * 4 + wave;     // 0..15, 128-pt window

    const float* __restrict__ sx = pcs + (size_t)b * 3 * N_PTS;
    const float* __restrict__ sy = sx + N_PTS;
    const float* __restrict__ sz = sy + N_PTS;

    const int qi = g * 64 + lane;
    const float qx = sx[qi], qy = sy[qi], qz = sz[qi];
    const v2f qx2 = {qx, qx}, qy2 = {qy, qy}, qz2 = {qz, qz};

    const int jbase = win * 128;               // uniform
    int* const mbase = out + (size_t)qg * 4096;

    #pragma unroll
    for (int i = 0; i < 4; ++i) {              // word w = win*4 + i
        unsigned m = 0;
        #pragma unroll
        for (int k = 30; k >= 0; k -= 2) {     // descending pairs: bits k+1,k
            const int j = jbase + i * 32 + k;  // uniform, even -> s_load
            const v2f px = *(const v2f*)(sx + j);
            const v2f py = *(const v2f*)(sy + j);
            const v2f pz = *(const v2f*)(sz + j);
            const v2f dx = px - qx2;
            const v2f dy = py - qy2;
            const v2f dz = pz - qz2;
            const v2f d2 = (dx * dx + dy * dy) + dz * dz;  // pk, no contract
            m = m + m + (unsigned)(d2.y < R2);
            m = m + m + (unsigned)(d2.x < R2);
        }
        mbase[(win * 4 + i) * 64 + lane] = (int)m;   // coalesced full lines
    }
}

// ---------------- K2: prefix + emit ----------------
// grid 512 (one per qg); block 512 thr = 8 waves; wave v owns words v*8..v*8+7
#define WAVES 8
__global__ __launch_bounds__(512, 4) void bq_emit_kernel(
    int* __restrict__ out)
{
    __shared__ int rows[64 * ROWPAD];
    __shared__ int cntS[WAVES][64];
    __shared__ int qfS[WAVES][64];

    const int qg   = blockIdx.x;
    const int tid  = threadIdx.x;
    const int wave = tid >> 6;
    const int lane = tid & 63;

    int* const reg = out + (size_t)qg * 4096;

    // coalesced mask reload: word w = wave*8+i, lane-stride 4B
    unsigned mask[8];
    #pragma unroll
    for (int i = 0; i < 8; ++i)
        mask[i] = (unsigned)reg[(wave * 8 + i) * 64 + lane];

    int cnt = 0;
    #pragma unroll
    for (int i = 0; i < 8; ++i) cnt += __builtin_popcount(mask[i]);
    int qf = -1;
    #pragma unroll
    for (int i = 0; i < 8; ++i) {
        if (qf < 0 && mask[i] != 0u)
            qf = (wave * 8 + i) * 32 + __builtin_ctz(mask[i]);
    }
    cntS[wave][lane] = cnt;
    qfS[wave][lane]  = qf;
    __syncthreads();      // also guarantees all mask loads complete

    int base = 0, tc = 0, gfirst = 0;
    #pragma unroll
    for (int w = 0; w < WAVES; ++w) {
        const int c = cntS[w][lane];
        const int f = qfS[w][lane];
        if (w < wave) base += c;
        gfirst = (tc == 0 && c > 0) ? f : gfirst;
        tc += c;
    }

    // sparse emit into LDS rows (disjoint slot ranges across waves)
    int slot = base;
    #pragma unroll
    for (int i = 0; i < 8; ++i) {
        unsigned m = mask[i];
        while (m != 0u && slot < K_OUT) {
            const int k = (int)__builtin_ctz(m);
            rows[lane * ROWPAD + slot] = (wave * 8 + i) * 32 + k;
            m &= m - 1u;
            ++slot;
        }
    }

    // pad: 8 slots per wave cover [0,64)
    #pragma unroll
    for (int s0 = 0; s0 < K_OUT / WAVES; ++s0) {
        const int s = wave * (K_OUT / WAVES) + s0;
        if (s >= tc) rows[lane * ROWPAD + s] = gfirst;
    }
    __syncthreads();

    // coalesced copy-out over the same region (row r = local query, col c)
    #pragma unroll
    for (int it = 0; it < (64 * K_OUT) / 512; ++it) {
        const int idx = it * 512 + tid;
        const int r = idx >> 6;
        const int c = idx & 63;
        reg[idx] = rows[r * ROWPAD + c];
    }
}

extern "C" void kernel_launch(void* const* d_in, const int* in_sizes, int n_in,
                              void* d_out, int out_size, void* d_ws, size_t ws_size,
                              hipStream_t stream) {
    const float* pcs = (const float*)d_in[0];
    int* out = (int*)d_out;
    bq_mask_kernel<<<2048, 256, 0, stream>>>(pcs, out);
    bq_emit_kernel<<<512, 512, 0, stream>>>(out);
}